// Round 3
// baseline (173.466 us; speedup 1.0000x reference)
//
#include <hip/hip_runtime.h>
#include <math.h>

#define CDIM 1024
#define RDIM 100
#define NBAGS 8192

typedef float floatx4 __attribute__((ext_vector_type(4)));
typedef short bf16x8 __attribute__((ext_vector_type(8)));

__device__ __forceinline__ float dot4(float4 a, float4 b) {
    return a.x * b.x + a.y * b.y + a.z * b.z + a.w * b.w;
}

// fp32 -> bf16 round-to-nearest-even
__device__ __forceinline__ short f2bf(float f) {
    unsigned int u = __builtin_bit_cast(unsigned int, f);
    u += 0x7FFFu + ((u >> 16) & 1u);
    return (short)(u >> 16);
}

// Kernel 1: one wave per bag, online softmax, X read once.
// Round-3 changes: (a) branchless online update (exp(-inf)=0 handles init),
// (b) explicit next-row prefetch issued before the current row's reduce,
// so HBM latency overlaps the compute chain instead of serializing with it.
__global__ __launch_bounds__(256) void bag_softmax_kernel(
    const float* __restrict__ X,
    const float* __restrict__ Constraints,
    const int* __restrict__ scope,
    const int* __restrict__ rel,
    float* __restrict__ bagbuf)
{
    const int wid  = threadIdx.x >> 6;
    const int lane = threadIdx.x & 63;
    const int bag  = blockIdx.x * 4 + wid;

    const int s = scope[2 * bag];
    const int e = scope[2 * bag + 1];
    const int r = rel[bag];

    const float4* conp = (const float4*)(Constraints + (size_t)r * CDIM);
    const float4 c0 = conp[lane];
    const float4 c1 = conp[lane + 64];
    const float4 c2 = conp[lane + 128];
    const float4 c3 = conp[lane + 192];

    float4 a0 = {0.f, 0.f, 0.f, 0.f};
    float4 a1 = {0.f, 0.f, 0.f, 0.f};
    float4 a2 = {0.f, 0.f, 0.f, 0.f};
    float4 a3 = {0.f, 0.f, 0.f, 0.f};
    float m = -INFINITY;
    float denom = 0.f;

    // preload first row
    const float4* xr = (const float4*)(X + (size_t)s * CDIM);
    float4 x0 = xr[lane];
    float4 x1 = xr[lane + 64];
    float4 x2 = xr[lane + 128];
    float4 x3 = xr[lane + 192];

    for (int row = s; row < e; ++row) {
        // Prefetch next row FIRST (unconditional address: last iter re-reads
        // current row -> L1 hit). These loads are independent of everything
        // below, so they overlap the reduce + update chain.
        const int nxt = (row + 1 < e) ? (row + 1) : row;
        const float4* nr = (const float4*)(X + (size_t)nxt * CDIM);
        float4 n0 = nr[lane];
        float4 n1 = nr[lane + 64];
        float4 n2 = nr[lane + 128];
        float4 n3 = nr[lane + 192];

        float p = dot4(x0, c0) + dot4(x1, c1) + dot4(x2, c2) + dot4(x3, c3);
        #pragma unroll
        for (int off = 1; off < 64; off <<= 1)
            p += __shfl_xor(p, off);

        // Branchless online-softmax update.
        const float newm = fmaxf(m, p);
        const float corr = __expf(m - newm);   // 1 if no new max; 0 on first row
        const float w    = __expf(p - newm);   // <=1
        denom = fmaf(denom, corr, w);
        a0.x = fmaf(a0.x, corr, w * x0.x); a0.y = fmaf(a0.y, corr, w * x0.y);
        a0.z = fmaf(a0.z, corr, w * x0.z); a0.w = fmaf(a0.w, corr, w * x0.w);
        a1.x = fmaf(a1.x, corr, w * x1.x); a1.y = fmaf(a1.y, corr, w * x1.y);
        a1.z = fmaf(a1.z, corr, w * x1.z); a1.w = fmaf(a1.w, corr, w * x1.w);
        a2.x = fmaf(a2.x, corr, w * x2.x); a2.y = fmaf(a2.y, corr, w * x2.y);
        a2.z = fmaf(a2.z, corr, w * x2.z); a2.w = fmaf(a2.w, corr, w * x2.w);
        a3.x = fmaf(a3.x, corr, w * x3.x); a3.y = fmaf(a3.y, corr, w * x3.y);
        a3.z = fmaf(a3.z, corr, w * x3.z); a3.w = fmaf(a3.w, corr, w * x3.w);
        m = newm;

        x0 = n0; x1 = n1; x2 = n2; x3 = n3;
    }

    const float inv = 1.0f / denom;
    float4* ob = (float4*)(bagbuf + (size_t)bag * CDIM);
    a0.x *= inv; a0.y *= inv; a0.z *= inv; a0.w *= inv;
    a1.x *= inv; a1.y *= inv; a1.z *= inv; a1.w *= inv;
    a2.x *= inv; a2.y *= inv; a2.z *= inv; a2.w *= inv;
    a3.x *= inv; a3.y *= inv; a3.z *= inv; a3.w *= inv;
    ob[lane]       = a0;
    ob[lane + 64]  = a1;
    ob[lane + 128] = a2;
    ob[lane + 192] = a3;
}

// Kernel 2 (unchanged): MFMA GEMM. out[b][r] = sum_c bag[b][c]*W[r][c] + bias[r].
__global__ __launch_bounds__(128) void bag_gemm_mfma(
    const float* __restrict__ bagbuf,
    const float* __restrict__ W,
    const float* __restrict__ bias,
    float* __restrict__ out)
{
    const int wid  = threadIdx.x >> 6;
    const int lane = threadIdx.x & 63;
    const int bag0 = (blockIdx.x * 2 + wid) * 16;
    const int ln15 = lane & 15;
    const int koff = (lane >> 4) * 8;

    floatx4 acc[7];
    #pragma unroll
    for (int t = 0; t < 7; ++t) acc[t] = (floatx4){0.f, 0.f, 0.f, 0.f};

    const float* aRow = bagbuf + (size_t)(bag0 + ln15) * CDIM + koff;

    for (int kc = 0; kc < CDIM / 32; ++kc) {
        const int k0 = kc * 32;

        float4 af0 = *(const float4*)(aRow + k0);
        float4 af1 = *(const float4*)(aRow + k0 + 4);
        bf16x8 a;
        a[0] = f2bf(af0.x); a[1] = f2bf(af0.y); a[2] = f2bf(af0.z); a[3] = f2bf(af0.w);
        a[4] = f2bf(af1.x); a[5] = f2bf(af1.y); a[6] = f2bf(af1.z); a[7] = f2bf(af1.w);

        #pragma unroll
        for (int t = 0; t < 7; ++t) {
            const int r = t * 16 + ln15;
            bf16x8 b = (bf16x8)0;
            if (r < RDIM) {
                const float* wp = W + (size_t)r * CDIM + k0 + koff;
                float4 w0 = *(const float4*)(wp);
                float4 w1 = *(const float4*)(wp + 4);
                b[0] = f2bf(w0.x); b[1] = f2bf(w0.y); b[2] = f2bf(w0.z); b[3] = f2bf(w0.w);
                b[4] = f2bf(w1.x); b[5] = f2bf(w1.y); b[6] = f2bf(w1.z); b[7] = f2bf(w1.w);
            }
            acc[t] = __builtin_amdgcn_mfma_f32_16x16x32_bf16(a, b, acc[t], 0, 0, 0);
        }
    }

    const int mbase = (lane >> 4) * 4;
    #pragma unroll
    for (int t = 0; t < 7; ++t) {
        const int r = t * 16 + ln15;
        if (r < RDIM) {
            const float bv = bias[r];
            #pragma unroll
            for (int reg = 0; reg < 4; ++reg) {
                const int bag = bag0 + mbase + reg;
                out[(size_t)bag * RDIM + r] = acc[t][reg] + bv;
            }
        }
    }
}

extern "C" void kernel_launch(void* const* d_in, const int* in_sizes, int n_in,
                              void* d_out, int out_size, void* d_ws, size_t ws_size,
                              hipStream_t stream) {
    const float* X    = (const float*)d_in[0];
    const float* Con  = (const float*)d_in[1];
    const float* W    = (const float*)d_in[2];
    const float* bias = (const float*)d_in[3];
    const int* scope  = (const int*)d_in[4];
    const int* rel    = (const int*)d_in[5];
    float* out = (float*)d_out;
    float* bagbuf = (float*)d_ws;   // NBAGS * CDIM * 4 = 33.6 MB

    bag_softmax_kernel<<<NBAGS / 4, 256, 0, stream>>>(X, Con, scope, rel, bagbuf);
    bag_gemm_mfma<<<NBAGS / 32, 128, 0, stream>>>(bagbuf, W, bias, out);
}

// Round 4
// 114.606 us; speedup vs baseline: 1.5136x; 1.5136x over previous
//
#include <hip/hip_runtime.h>
#include <math.h>

#define CDIM 1024
#define RDIM 100
#define NBAGS 8192
#define CHUNK 4

typedef float floatx4 __attribute__((ext_vector_type(4)));
typedef short bf16x8 __attribute__((ext_vector_type(8)));

__device__ __forceinline__ float dot4(float4 a, float4 b) {
    return a.x * b.x + a.y * b.y + a.z * b.z + a.w * b.w;
}

// fp32 -> bf16 round-to-nearest-even
__device__ __forceinline__ short f2bf(float f) {
    unsigned int u = __builtin_bit_cast(unsigned int, f);
    u += 0x7FFFu + ((u >> 16) & 1u);
    return (short)(u >> 16);
}

// Kernel 1: one wave per bag, online softmax over chunks of 4 rows.
// 4 rows (16 float4 loads) in registers + next-chunk prefetch in flight:
// dots and butterfly reduces are independent across the 4 rows, the serial
// online-update happens once per chunk instead of once per row.
__global__ __launch_bounds__(256) void bag_softmax_kernel(
    const float* __restrict__ X,
    const float* __restrict__ Constraints,
    const int* __restrict__ scope,
    const int* __restrict__ rel,
    float* __restrict__ bagbuf)
{
    const int wid  = threadIdx.x >> 6;
    const int lane = threadIdx.x & 63;
    const int bag  = blockIdx.x * 4 + wid;

    const int s = scope[2 * bag];
    const int e = scope[2 * bag + 1];
    const int r = rel[bag];

    float4 c[4];
    {
        const float4* conp = (const float4*)(Constraints + (size_t)r * CDIM);
        c[0] = conp[lane];
        c[1] = conp[lane + 64];
        c[2] = conp[lane + 128];
        c[3] = conp[lane + 192];
    }

    float4 a[4];
    #pragma unroll
    for (int q = 0; q < 4; ++q) a[q] = (float4){0.f, 0.f, 0.f, 0.f};
    float m = -INFINITY;
    float denom = 0.f;

    float4 xa[CHUNK][4];   // current chunk (rows j, quarters q)
    float4 xb[CHUNK][4];   // prefetch chunk

    // prologue: load first chunk (rows clamped to e-1)
    #pragma unroll
    for (int j = 0; j < CHUNK; ++j) {
        int ri = s + j; ri = (ri < e) ? ri : (e - 1);
        const float4* xr = (const float4*)(X + (size_t)ri * CDIM);
        xa[j][0] = xr[lane];
        xa[j][1] = xr[lane + 64];
        xa[j][2] = xr[lane + 128];
        xa[j][3] = xr[lane + 192];
    }

    for (int base = s; base < e; base += CHUNK) {
        // prefetch next chunk FIRST (clamped; final iter re-reads = L1 hits)
        const int nb = (base + CHUNK < e) ? (base + CHUNK) : base;
        #pragma unroll
        for (int j = 0; j < CHUNK; ++j) {
            int ri = nb + j; ri = (ri < e) ? ri : (e - 1);
            const float4* xr = (const float4*)(X + (size_t)ri * CDIM);
            xb[j][0] = xr[lane];
            xb[j][1] = xr[lane + 64];
            xb[j][2] = xr[lane + 128];
            xb[j][3] = xr[lane + 192];
        }

        // 4 independent dots
        float p[CHUNK];
        #pragma unroll
        for (int j = 0; j < CHUNK; ++j)
            p[j] = dot4(xa[j][0], c[0]) + dot4(xa[j][1], c[1])
                 + dot4(xa[j][2], c[2]) + dot4(xa[j][3], c[3]);

        // 4 independent butterfly reduces (pipelined, not serial)
        #pragma unroll
        for (int off = 1; off < 64; off <<= 1) {
            #pragma unroll
            for (int j = 0; j < CHUNK; ++j)
                p[j] += __shfl_xor(p[j], off);
        }

        // mask padded rows
        #pragma unroll
        for (int j = 0; j < CHUNK; ++j)
            if (base + j >= e) p[j] = -INFINITY;

        // chunk-level online-softmax merge
        const float cm   = fmaxf(fmaxf(p[0], p[1]), fmaxf(p[2], p[3]));
        const float newm = fmaxf(m, cm);
        const float corr = __expf(m - newm);        // 0 on first chunk
        const float w0 = __expf(p[0] - newm);
        const float w1 = __expf(p[1] - newm);
        const float w2 = __expf(p[2] - newm);
        const float w3 = __expf(p[3] - newm);
        denom = fmaf(denom, corr, (w0 + w1) + (w2 + w3));
        m = newm;

        #pragma unroll
        for (int q = 0; q < 4; ++q) {
            float tx = w0 * xa[0][q].x; tx = fmaf(w1, xa[1][q].x, tx);
            tx = fmaf(w2, xa[2][q].x, tx); tx = fmaf(w3, xa[3][q].x, tx);
            float ty = w0 * xa[0][q].y; ty = fmaf(w1, xa[1][q].y, ty);
            ty = fmaf(w2, xa[2][q].y, ty); ty = fmaf(w3, xa[3][q].y, ty);
            float tz = w0 * xa[0][q].z; tz = fmaf(w1, xa[1][q].z, tz);
            tz = fmaf(w2, xa[2][q].z, tz); tz = fmaf(w3, xa[3][q].z, tz);
            float tw = w0 * xa[0][q].w; tw = fmaf(w1, xa[1][q].w, tw);
            tw = fmaf(w2, xa[2][q].w, tw); tw = fmaf(w3, xa[3][q].w, tw);
            a[q].x = fmaf(a[q].x, corr, tx);
            a[q].y = fmaf(a[q].y, corr, ty);
            a[q].z = fmaf(a[q].z, corr, tz);
            a[q].w = fmaf(a[q].w, corr, tw);
        }

        // rotate buffers (register renaming, no copies emitted)
        #pragma unroll
        for (int j = 0; j < CHUNK; ++j)
            #pragma unroll
            for (int q = 0; q < 4; ++q)
                xa[j][q] = xb[j][q];
    }

    const float inv = 1.0f / denom;
    float4* ob = (float4*)(bagbuf + (size_t)bag * CDIM);
    #pragma unroll
    for (int q = 0; q < 4; ++q) {
        a[q].x *= inv; a[q].y *= inv; a[q].z *= inv; a[q].w *= inv;
        ob[lane + q * 64] = a[q];
    }
}

// Kernel 2 (unchanged): MFMA GEMM. out[b][r] = sum_c bag[b][c]*W[r][c] + bias[r].
__global__ __launch_bounds__(128) void bag_gemm_mfma(
    const float* __restrict__ bagbuf,
    const float* __restrict__ W,
    const float* __restrict__ bias,
    float* __restrict__ out)
{
    const int wid  = threadIdx.x >> 6;
    const int lane = threadIdx.x & 63;
    const int bag0 = (blockIdx.x * 2 + wid) * 16;
    const int ln15 = lane & 15;
    const int koff = (lane >> 4) * 8;

    floatx4 acc[7];
    #pragma unroll
    for (int t = 0; t < 7; ++t) acc[t] = (floatx4){0.f, 0.f, 0.f, 0.f};

    const float* aRow = bagbuf + (size_t)(bag0 + ln15) * CDIM + koff;

    for (int kc = 0; kc < CDIM / 32; ++kc) {
        const int k0 = kc * 32;

        float4 af0 = *(const float4*)(aRow + k0);
        float4 af1 = *(const float4*)(aRow + k0 + 4);
        bf16x8 aa;
        aa[0] = f2bf(af0.x); aa[1] = f2bf(af0.y); aa[2] = f2bf(af0.z); aa[3] = f2bf(af0.w);
        aa[4] = f2bf(af1.x); aa[5] = f2bf(af1.y); aa[6] = f2bf(af1.z); aa[7] = f2bf(af1.w);

        #pragma unroll
        for (int t = 0; t < 7; ++t) {
            const int r = t * 16 + ln15;
            bf16x8 b = (bf16x8)0;
            if (r < RDIM) {
                const float* wp = W + (size_t)r * CDIM + k0 + koff;
                float4 w0 = *(const float4*)(wp);
                float4 w1 = *(const float4*)(wp + 4);
                b[0] = f2bf(w0.x); b[1] = f2bf(w0.y); b[2] = f2bf(w0.z); b[3] = f2bf(w0.w);
                b[4] = f2bf(w1.x); b[5] = f2bf(w1.y); b[6] = f2bf(w1.z); b[7] = f2bf(w1.w);
            }
            acc[t] = __builtin_amdgcn_mfma_f32_16x16x32_bf16(aa, b, acc[t], 0, 0, 0);
        }
    }

    const int mbase = (lane >> 4) * 4;
    #pragma unroll
    for (int t = 0; t < 7; ++t) {
        const int r = t * 16 + ln15;
        if (r < RDIM) {
            const float bv = bias[r];
            #pragma unroll
            for (int reg = 0; reg < 4; ++reg) {
                const int bag = bag0 + mbase + reg;
                out[(size_t)bag * RDIM + r] = acc[t][reg] + bv;
            }
        }
    }
}

extern "C" void kernel_launch(void* const* d_in, const int* in_sizes, int n_in,
                              void* d_out, int out_size, void* d_ws, size_t ws_size,
                              hipStream_t stream) {
    const float* X    = (const float*)d_in[0];
    const float* Con  = (const float*)d_in[1];
    const float* W    = (const float*)d_in[2];
    const float* bias = (const float*)d_in[3];
    const int* scope  = (const int*)d_in[4];
    const int* rel    = (const int*)d_in[5];
    float* out = (float*)d_out;
    float* bagbuf = (float*)d_ws;   // NBAGS * CDIM * 4 = 33.6 MB

    bag_softmax_kernel<<<NBAGS / 4, 256, 0, stream>>>(X, Con, scope, rel, bagbuf);
    bag_gemm_mfma<<<NBAGS / 32, 128, 0, stream>>>(bagbuf, W, bias, out);
}